// Round 9
// baseline (72.029 us; speedup 1.0000x reference)
//
#include <hip/hip_runtime.h>

typedef __attribute__((ext_vector_type(8)))  __bf16 bf16x8;
typedef __attribute__((ext_vector_type(16))) float  f32x16;

#define D_IN  128
#define N_OUT 32
#define K129  129
#define WROW  16512          // 128*129 floats per W row
#define KE    144            // extended K for W: col 128 = wlin, 129..143 = 0
#define NT    8              // m-tiles (32 rows) per block = 256-row run
#define XQ_ELEMS (16384 * 128)
#define WQ_ELEMS (32 * 128 * KE)

// slot -> i permutation within each 32-row block: makes each lane's acc rows
// line up with the 8-elem col chunks its own B-fragments hold. (verified r5-r8)
__host__ __device__ __forceinline__ int permSlot(int s) {
    int q = s >> 3, h = (s >> 2) & 1, j = s & 3;
    return 16 * (q >> 1) + 8 * h + 4 * (q & 1) + j;
}

// ---- fused prep: x -> bf16 [16384][128]; W -> bf16 [32][128 slots][144] ----
__global__ void prep(const float* __restrict__ x, const float* __restrict__ W,
                     __bf16* __restrict__ xq, __bf16* __restrict__ Wq) {
    int t = blockIdx.x * 256 + threadIdx.x;          // 1024*256 = 262144 threads
    {
        const float4* s = reinterpret_cast<const float4*>(x) + (size_t)t * 2;
        float4 a = s[0], b = s[1];
        bf16x8 v = { (__bf16)a.x, (__bf16)a.y, (__bf16)a.z, (__bf16)a.w,
                     (__bf16)b.x, (__bf16)b.y, (__bf16)b.z, (__bf16)b.w };
        reinterpret_cast<bf16x8*>(xq)[t] = v;
    }
    for (int e = t; e < WQ_ELEMS; e += 262144) {
        int oi = e / KE, k = e - oi * KE;            // oi = o*128 + slot_g
        int o = oi >> 7, sg = oi & 127;
        int i = (sg & ~31) + permSlot(sg & 31);      // permuted source row
        float v = (k <= D_IN) ? W[o * WROW + i * K129 + k] : 0.f;  // k==128 -> wlin
        Wq[e] = (__bf16)v;
    }
}

// dot for slot-block G (literal index): acc reg (q,j) pairs with
// Bf[2G + (q>>1)] element [4(q&1)+j]; 4 independent partials break the chain.
#define DOT(G)                                                                     \
    _Pragma("unroll")                                                              \
    for (int q = 0; q < 4; ++q)                                                    \
        _Pragma("unroll")                                                          \
        for (int j = 0; j < 4; ++j)                                                \
            sq[q] += a[q * 4 + j] * (float)Bf[2 * (G) + (q >> 1)][4 * (q & 1) + j];

// Block = 4 waves = 1 o, each wave one 32-i slot-block over a shared 256-row
// run. No LDS staging; raw per-tile s_barrier keeps waves lockstep for L1
// sharing. All register arrays literal-indexed (switch on wave-uniform g).
template<int PREP>
__global__ __launch_bounds__(256, 4) void quad9(
    const float* __restrict__ x, const float* __restrict__ W,
    const __bf16* __restrict__ xq, const __bf16* __restrict__ Wq,
    const float* __restrict__ bias, float* __restrict__ out)
{
    __shared__ float red[4][NT][32];      // [g][tile][b]  4 KB

    const int tid  = threadIdx.x;
    const int lane = tid & 63;
    const int g    = tid >> 6;            // wave = slot-block 0..3 (i in [32g,32g+32))
    const int b32  = lane & 31, hi = lane >> 5;

    // grid 2048 = 8 XCD x (8 runs x 32 o): same-run blocks adjacent within XCD
    const int bid = blockIdx.x;
    const int xcd = bid & 7, idx = bid >> 3;
    const int run = xcd * 8 + (idx >> 5); // 0..63
    const int o   = idx & 31;
    const long rbase = (long)run * (NT * 32);
    const float bias_o = bias[o];

    // ---- stationary A fragment: slot rows g*32 + b32, k = hi*8 + r ----
    bf16x8 A[9];
    if (PREP) {
        const __bf16* base = Wq + ((size_t)o * 128 + g * 32 + b32) * KE + hi * 8;
        #pragma unroll
        for (int ks = 0; ks < 9; ++ks)
            A[ks] = *reinterpret_cast<const bf16x8*>(base + ks * 16);
    } else {
        const int i = g * 32 + permSlot(b32);
        const float* wr = W + (size_t)o * WROW + (size_t)i * K129;
        #pragma unroll
        for (int ks = 0; ks < 8; ++ks) {
            bf16x8 f;
            #pragma unroll
            for (int r = 0; r < 8; ++r) f[r] = (__bf16)wr[ks * 16 + hi * 8 + r];
            A[ks] = f;
        }
        bf16x8 f;
        #pragma unroll
        for (int r = 0; r < 8; ++r) f[r] = (__bf16)0.f;
        if (hi == 0) f[0] = (__bf16)wr[128];          // wlin at k=128
        A[8] = f;
    }

    // constant ks=8 B fragment: x~[b,128]=1, rest 0
    bf16x8 B8c;
    #pragma unroll
    for (int r = 0; r < 8; ++r) B8c[r] = (__bf16)0.f;
    if (hi == 0) B8c[0] = (__bf16)1.0f;

    // per-lane streaming base: row rbase+b32, element offset hi*8
    const __bf16* bp = xq + (rbase + b32) * D_IN + hi * 8;
    const float*  fp = x  + (rbase + b32) * D_IN + hi * 8;

    #pragma unroll
    for (int t = 0; t < NT; ++t) {
        if (t > 0) __builtin_amdgcn_s_barrier();   // lockstep -> L1 co-hits

        // Bf[ks] = logical chunk (2ks+hi) of row (rbase + t*32 + b32)
        bf16x8 Bf[8];
        if (PREP) {
            #pragma unroll
            for (int ks = 0; ks < 8; ++ks)
                Bf[ks] = *reinterpret_cast<const bf16x8*>(bp + t * 32 * D_IN + ks * 16);
        } else {
            #pragma unroll
            for (int ks = 0; ks < 8; ++ks) {
                const float* q4 = fp + t * 32 * D_IN + ks * 16;
                float4 u0 = *(const float4*)q4, u1 = *(const float4*)(q4 + 4);
                bf16x8 f = { (__bf16)u0.x,(__bf16)u0.y,(__bf16)u0.z,(__bf16)u0.w,
                             (__bf16)u1.x,(__bf16)u1.y,(__bf16)u1.z,(__bf16)u1.w };
                Bf[ks] = f;
            }
        }

        f32x16 a;
        #pragma unroll
        for (int r = 0; r < 16; ++r) a[r] = 0.f;
        #pragma unroll
        for (int ks = 0; ks < 8; ++ks)
            a = __builtin_amdgcn_mfma_f32_32x32x16_bf16(A[ks], Bf[ks], a, 0, 0, 0);
        a = __builtin_amdgcn_mfma_f32_32x32x16_bf16(A[8], B8c, a, 0, 0, 0);

        float sq[4] = {0.f, 0.f, 0.f, 0.f};
        switch (g) {                       // wave-uniform; keeps indices literal
            case 0: DOT(0); break;
            case 1: DOT(1); break;
            case 2: DOT(2); break;
            default: DOT(3); break;
        }
        float s = (sq[0] + sq[1]) + (sq[2] + sq[3]);
        s += __shfl_xor(s, 32);
        if (hi == 0) red[g][t][b32] = s;
    }

    // ---- one-time cross-wave combine + store (all 64 lanes of wave 0) ----
    __syncthreads();
    if (g == 0) {
        #pragma unroll
        for (int m = 0; m < NT / 2; ++m) {
            int t = m * 2 + hi;
            out[(rbase + (long)t * 32 + b32) * N_OUT + o] =
                (red[0][t][b32] + red[1][t][b32]) +
                (red[2][t][b32] + red[3][t][b32]) + bias_o;
        }
    }
}

extern "C" void kernel_launch(void* const* d_in, const int* in_sizes, int n_in,
                              void* d_out, int out_size, void* d_ws, size_t ws_size,
                              hipStream_t stream) {
    const float* x    = (const float*)d_in[0];
    const float* W    = (const float*)d_in[1];
    const float* bias = (const float*)d_in[2];
    float* out = (float*)d_out;

    const size_t need = (size_t)(XQ_ELEMS + WQ_ELEMS) * sizeof(__bf16);  // ~5.4 MB
    if (ws_size >= need) {
        __bf16* xq = (__bf16*)d_ws;
        __bf16* Wq = xq + XQ_ELEMS;
        prep<<<1024, 256, 0, stream>>>(x, W, xq, Wq);
        quad9<1><<<2048, 256, 0, stream>>>(x, W, xq, Wq, bias, out);
    } else {
        quad9<0><<<2048, 256, 0, stream>>>(x, W, (const __bf16*)nullptr,
                                           (const __bf16*)nullptr, bias, out);
    }
}

// Round 10
// 32.527 us; speedup vs baseline: 2.2145x; 2.2145x over previous
//
#include <hip/hip_runtime.h>

typedef __attribute__((ext_vector_type(8)))  __bf16 bf16x8;
typedef __attribute__((ext_vector_type(16))) float  f32x16;
typedef unsigned int uint32;

#define D_IN  128
#define N_OUT 32
#define K129  129
#define WROW  16512          // 128*129 floats per W row
#define KE    144            // extended K for W: col 128 = wlin, 129..143 = 0
#define NT    8              // m-tiles (32 rows) per block = 256-row run
#define XQ_ELEMS (16384 * 128)
#define WQ_ELEMS (32 * 128 * KE)

// slot -> i permutation within each 32-row block: makes each lane's acc rows
// line up with the 8-elem col chunks its own B-fragments hold. (verified r5-r9)
__host__ __device__ __forceinline__ int permSlot(int s) {
    int q = s >> 3, h = (s >> 2) & 1, j = s & 3;
    return 16 * (q >> 1) + 8 * h + 4 * (q & 1) + j;
}

// ---- fused prep: x -> bf16 [16384][128]; W -> bf16 [32][128 slots][144] ----
__global__ void prep(const float* __restrict__ x, const float* __restrict__ W,
                     __bf16* __restrict__ xq, __bf16* __restrict__ Wq) {
    int t = blockIdx.x * 256 + threadIdx.x;          // 1024*256 = 262144 threads
    {
        const float4* s = reinterpret_cast<const float4*>(x) + (size_t)t * 2;
        float4 a = s[0], b = s[1];
        bf16x8 v = { (__bf16)a.x, (__bf16)a.y, (__bf16)a.z, (__bf16)a.w,
                     (__bf16)b.x, (__bf16)b.y, (__bf16)b.z, (__bf16)b.w };
        reinterpret_cast<bf16x8*>(xq)[t] = v;
    }
    for (int e = t; e < WQ_ELEMS; e += 262144) {
        int oi = e / KE, k = e - oi * KE;            // oi = o*128 + slot_g
        int o = oi >> 7, sg = oi & 127;
        int i = (sg & ~31) + permSlot(sg & 31);      // permuted source row
        float v = (k <= D_IN) ? W[o * WROW + i * K129 + k] : 0.f;  // k==128 -> wlin
        Wq[e] = (__bf16)v;
    }
}

// LDS tile: [32 rows][16 chunks of 16B], chunk-XOR swizzled (phys c = log c ^ (r&15)).
// One global_load_lds per thread stages the whole 8KB tile (512 x 16B).
// Wave w writes phys chunks [w*64, w*64+64): dest wave-uniform base, rule-21 safe.
#define STAGE(BUF, T)                                                              \
  do {                                                                             \
    if (PREP) {                                                                    \
      __builtin_amdgcn_global_load_lds(                                            \
        (const __attribute__((address_space(1))) uint32*)                          \
          (xq + ((rbase + (long)(T) * 32 + rs) * D_IN + cs * 8)),                  \
        (__attribute__((address_space(3))) uint32*)(&tile[BUF][wave * 512]),       \
        16, 0, 0);                                                                 \
    } else {                                                                       \
      const float* s0 = x + (rbase + (long)(T) * 32 + rs) * D_IN + cs * 8;         \
      float4 a0 = *(const float4*)s0, a1 = *(const float4*)(s0 + 4);               \
      bf16x8 v0 = { (__bf16)a0.x,(__bf16)a0.y,(__bf16)a0.z,(__bf16)a0.w,           \
                    (__bf16)a1.x,(__bf16)a1.y,(__bf16)a1.z,(__bf16)a1.w };         \
      *(bf16x8*)&tile[BUF][(size_t)tid * 8] = v0;                                  \
    }                                                                              \
  } while (0)

// One m-tile: 8 swizzled ds_read_b128 -> 2 blocks x 9 MFMA (setprio-wrapped);
// epilogue dot reuses the SAME B-frag registers. ALL Bf indices are literal:
// ctl is a fully-unrolled loop var, sub is handled by a wave-uniform branch
// (rule #20: runtime-indexed reg arrays -> scratch; this was quad7's bug).
#define COMPUTE(BUF, MT)                                                           \
  {                                                                                \
    const char* tb = (const char*)&tile[BUF][0];                                   \
    bf16x8 Bf[8];                                                                  \
    _Pragma("unroll")                                                              \
    for (int ks = 0; ks < 8; ++ks)                                                 \
      Bf[ks] = *reinterpret_cast<const bf16x8*>(tb + laneB[ks]);                   \
    float sq[4] = {0.f, 0.f, 0.f, 0.f};                                            \
    __builtin_amdgcn_s_setprio(1);                                                 \
    _Pragma("unroll")                                                              \
    for (int ctl = 0; ctl < 2; ++ctl) {                                            \
      f32x16 a;                                                                    \
      _Pragma("unroll")                                                            \
      for (int r = 0; r < 16; ++r) a[r] = 0.f;                                     \
      _Pragma("unroll")                                                            \
      for (int ks = 0; ks < 8; ++ks)                                               \
        a = __builtin_amdgcn_mfma_f32_32x32x16_bf16(A[ctl][ks], Bf[ks], a, 0,0,0); \
      a = __builtin_amdgcn_mfma_f32_32x32x16_bf16(A[ctl][8], B8c, a, 0, 0, 0);     \
      if (sub == 0) {                                                              \
        _Pragma("unroll")                                                          \
        for (int q = 0; q < 4; ++q)                                                \
          _Pragma("unroll")                                                        \
          for (int j = 0; j < 4; ++j)                                              \
            sq[q] += a[q * 4 + j] * (float)Bf[2 * ctl + (q >> 1)][4 * (q & 1) + j];\
      } else {                                                                     \
        _Pragma("unroll")                                                          \
        for (int q = 0; q < 4; ++q)                                                \
          _Pragma("unroll")                                                        \
          for (int j = 0; j < 4; ++j)                                              \
            sq[q] += a[q*4 + j] * (float)Bf[4 + 2*ctl + (q >> 1)][4*(q & 1) + j];  \
      }                                                                            \
    }                                                                              \
    __builtin_amdgcn_s_setprio(0);                                                 \
    float s = (sq[0] + sq[1]) + (sq[2] + sq[3]);                                   \
    s += __shfl_xor(s, 32);                                                        \
    sArr[MT] = s;                                                                  \
  }

#define WAITV(N) asm volatile("s_waitcnt vmcnt(" #N ")" ::: "memory")

// Counted-vmcnt pipeline iteration: wait own stage-T load (leave newer in
// flight), raw barrier (NO vmcnt(0) drain), issue stage T+3 into the buffer
// everyone finished reading at T-1, then compute tile T.
#define ITER(T, VN)                                                                \
  {                                                                                \
    WAITV(VN);                                                                     \
    __builtin_amdgcn_s_barrier();                                                  \
    asm volatile("" ::: "memory");                                                 \
    if ((T) + 3 < NT) STAGE(((T) + 3) & 3, (T) + 3);                               \
    COMPUTE((T) & 3, (T));                                                         \
  }

// Block = 8 waves = 4 o's x 2 i-halves over one shared 256-row run. Each wave:
// A[2][9] stationary (72 regs); x 4-deep buffered in LDS, 3 stages in flight.
template<int PREP>
__global__ __launch_bounds__(512, 2) void quad10(
    const float* __restrict__ x, const float* __restrict__ W,
    const __bf16* __restrict__ xq, const __bf16* __restrict__ Wq,
    const float* __restrict__ bias, float* __restrict__ out)
{
    __shared__ __align__(16) __bf16 tile[4][32 * 128];   // 4 x 8KB, swizzled
    __shared__ float red[4][2][NT][32];                  // [o4][sub][mt][b] 8KB

    const int tid  = threadIdx.x;
    const int lane = tid & 63;
    const int wave = tid >> 6;              // 0..7
    const int o4   = wave >> 1;             // o within group
    const int sub  = wave & 1;              // i-half (0: i<64, 1: i>=64)
    const int b32  = lane & 31, hi = lane >> 5;

    // grid 512 = 8 XCD x (8 runs x 8 o-groups): same-XCD blocks share x runs
    const int bid = blockIdx.x;
    const int xcd = bid & 7, idx = bid >> 3;
    const int run = xcd * 8 + (idx & 7);    // 0..63
    const int og  = idx >> 3;               // 0..7
    const int o   = og * 4 + o4;
    const long rbase = (long)run * (NT * 32);
    const float bias_o = bias[o];

    // ---- stationary A fragments: slot rows (sub*2+ctl)*32 + b32, k = hi*8+r ----
    bf16x8 A[2][9];
    #pragma unroll
    for (int ctl = 0; ctl < 2; ++ctl) {
        const int g = sub * 2 + ctl;
        if (PREP) {
            const __bf16* base = Wq + ((size_t)o * 128 + g * 32 + b32) * KE + hi * 8;
            #pragma unroll
            for (int ks = 0; ks < 9; ++ks)
                A[ctl][ks] = *reinterpret_cast<const bf16x8*>(base + ks * 16);
        } else {
            const int i = g * 32 + permSlot(b32);
            const float* wr = W + (size_t)o * WROW + (size_t)i * K129;
            #pragma unroll
            for (int ks = 0; ks < 8; ++ks) {
                bf16x8 f;
                #pragma unroll
                for (int r = 0; r < 8; ++r) f[r] = (__bf16)wr[ks * 16 + hi * 8 + r];
                A[ctl][ks] = f;
            }
            bf16x8 f;
            #pragma unroll
            for (int r = 0; r < 8; ++r) f[r] = (__bf16)0.f;
            if (hi == 0) f[0] = (__bf16)wr[128];         // wlin at k=128
            A[ctl][8] = f;
        }
    }

    // constant ks=8 B fragment: x~[b,128]=1, rest 0
    bf16x8 B8c;
    #pragma unroll
    for (int r = 0; r < 8; ++r) B8c[r] = (__bf16)0.f;
    if (hi == 0) B8c[0] = (__bf16)1.0f;

    // staging mapping: thread -> phys chunk tid; src pre-swizzled (inverse XOR)
    const int rs = tid >> 4, cs = (tid & 15) ^ (rs & 15);

    // swizzled ds_read byte offsets (row = b32, logical chunk 2ks+hi)
    const int rm = b32 & 15;
    int laneB[8];
    #pragma unroll
    for (int ks = 0; ks < 8; ++ks)
        laneB[ks] = b32 * 256 + (((ks * 2 + hi) ^ rm) << 4);

    float sArr[NT];

    // prologue: 3 stages in flight (1 vmem op each per thread)
    STAGE(0, 0);
    STAGE(1, 1);
    STAGE(2, 2);

    ITER(0, 2); ITER(1, 2); ITER(2, 2); ITER(3, 2);
    ITER(4, 2); ITER(5, 2); ITER(6, 1); ITER(7, 0);

    // ---- one-time cross-sub combine + store ----
    if (hi == 0) {
        #pragma unroll
        for (int mt = 0; mt < NT; ++mt) red[o4][sub][mt][b32] = sArr[mt];
    }
    __syncthreads();
    if (sub == 0 && hi == 0) {
        #pragma unroll
        for (int mt = 0; mt < NT; ++mt)
            out[(rbase + (long)mt * 32 + b32) * N_OUT + o] =
                red[o4][0][mt][b32] + red[o4][1][mt][b32] + bias_o;
    }
}

extern "C" void kernel_launch(void* const* d_in, const int* in_sizes, int n_in,
                              void* d_out, int out_size, void* d_ws, size_t ws_size,
                              hipStream_t stream) {
    const float* x    = (const float*)d_in[0];
    const float* W    = (const float*)d_in[1];
    const float* bias = (const float*)d_in[2];
    float* out = (float*)d_out;

    const size_t need = (size_t)(XQ_ELEMS + WQ_ELEMS) * sizeof(__bf16);  // ~5.4 MB
    if (ws_size >= need) {
        __bf16* xq = (__bf16*)d_ws;
        __bf16* Wq = xq + XQ_ELEMS;
        prep<<<1024, 256, 0, stream>>>(x, W, xq, Wq);
        quad10<1><<<512, 512, 0, stream>>>(x, W, xq, Wq, bias, out);
    } else {
        quad10<0><<<512, 512, 0, stream>>>(x, W, (const __bf16*)nullptr,
                                           (const __bf16*)nullptr, bias, out);
    }
}

// Round 11
// 31.282 us; speedup vs baseline: 2.3025x; 1.0398x over previous
//
#include <hip/hip_runtime.h>

typedef __attribute__((ext_vector_type(8)))  __bf16 bf16x8;
typedef __attribute__((ext_vector_type(16))) float  f32x16;
typedef unsigned int uint32;

#define D_IN  128
#define N_OUT 32
#define K129  129
#define WROW  16512          // 128*129 floats per W row
#define KE    144            // extended K for W: col 128 = wlin, 129..143 = 0
#define NT    8              // m-tiles (32 rows) per block = 256-row run
#define XQ_ELEMS (16384 * 128)
#define WQ_ELEMS (32 * 128 * KE)

// slot -> i permutation within each 32-row block: makes each lane's acc rows
// line up with the 8-elem col chunks its own B-fragments hold. (verified r5-r10)
__host__ __device__ __forceinline__ int permSlot(int s) {
    int q = s >> 3, h = (s >> 2) & 1, j = s & 3;
    return 16 * (q >> 1) + 8 * h + 4 * (q & 1) + j;
}

// ---- prep, pow2-mapped (no integer division anywhere) ----
// t < 262144          : x -> bf16 [16384][128]  (one bf16x8 per thread)
// 262144..327679      : Wq quadratic part: oi = t>>4, octet = t&15 (k = oct*8..+7)
// 327680..335871      : Wq tail: k = 128..143 (wlin at 128, zeros after)
__global__ void prep(const float* __restrict__ x, const float* __restrict__ W,
                     __bf16* __restrict__ xq, __bf16* __restrict__ Wq) {
    int t = blockIdx.x * 256 + threadIdx.x;
    if (t < 262144) {
        const float4* s = reinterpret_cast<const float4*>(x) + (size_t)t * 2;
        float4 a = s[0], b = s[1];
        bf16x8 v = { (__bf16)a.x, (__bf16)a.y, (__bf16)a.z, (__bf16)a.w,
                     (__bf16)b.x, (__bf16)b.y, (__bf16)b.z, (__bf16)b.w };
        reinterpret_cast<bf16x8*>(xq)[t] = v;
    } else if (t < 327680) {
        int t2 = t - 262144;
        int oi = t2 >> 4, oct = t2 & 15;     // oi = o*128 + slot
        int o = oi >> 7, sg = oi & 127;
        int i = (sg & ~31) + permSlot(sg & 31);
        const float* src = W + (size_t)o * WROW + (size_t)i * K129 + oct * 8;
        bf16x8 v;
        #pragma unroll
        for (int r = 0; r < 8; ++r) v[r] = (__bf16)src[r];
        *reinterpret_cast<bf16x8*>(Wq + (size_t)oi * KE + oct * 8) = v;
    } else if (t < 335872) {
        int t3 = t - 327680;
        int oi = t3 >> 1, h = t3 & 1;
        int o = oi >> 7, sg = oi & 127;
        int i = (sg & ~31) + permSlot(sg & 31);
        bf16x8 v;
        #pragma unroll
        for (int r = 0; r < 8; ++r) v[r] = (__bf16)0.f;
        if (h == 0) v[0] = (__bf16)W[(size_t)o * WROW + (size_t)i * K129 + 128];
        *reinterpret_cast<bf16x8*>(Wq + (size_t)oi * KE + 128 + h * 8) = v;
    }
}

// LDS tile: [32 rows][16 chunks of 16B], chunk-XOR swizzled (phys c = log c ^ (r&15)).
// 256 threads stage 512 chunks: thread covers phys chunks {wave*128+lane, +64};
// global_load_lds dest is wave-uniform base + lane*16 (rule-21 safe), source
// pre-swizzled. (identical to the verified quad4/quad5 staging)
#define STAGE(BUF, T)                                                              \
  do {                                                                             \
    if (PREP) {                                                                    \
      __builtin_amdgcn_global_load_lds(                                            \
        (const __attribute__((address_space(1))) uint32*)                          \
          (xq + ((rbase + (long)(T) * 32 + r0s) * D_IN + c0s * 8)),                \
        (__attribute__((address_space(3))) uint32*)(&tile[BUF][wave * 1024]),      \
        16, 0, 0);                                                                 \
      __builtin_amdgcn_global_load_lds(                                            \
        (const __attribute__((address_space(1))) uint32*)                          \
          (xq + ((rbase + (long)(T) * 32 + r1s) * D_IN + c1s * 8)),                \
        (__attribute__((address_space(3))) uint32*)(&tile[BUF][wave * 1024 + 512]),\
        16, 0, 0);                                                                 \
    } else {                                                                       \
      const float* s0 = x + (rbase + (long)(T) * 32 + r0s) * D_IN + c0s * 8;       \
      const float* s1 = x + (rbase + (long)(T) * 32 + r1s) * D_IN + c1s * 8;       \
      bf16x8 v0, v1;                                                               \
      _Pragma("unroll")                                                            \
      for (int r = 0; r < 8; ++r) { v0[r] = (__bf16)s0[r]; v1[r] = (__bf16)s1[r]; }\
      *(bf16x8*)&tile[BUF][(size_t)p0 * 8] = v0;                                   \
      *(bf16x8*)&tile[BUF][(size_t)p1 * 8] = v1;                                   \
    }                                                                              \
  } while (0)

// One m-tile: 8 swizzled ds_read_b128 -> 2 blocks x 9 MFMA (setprio-wrapped);
// epilogue dot reuses the SAME B-frag registers. All Bf indices literal (ctl
// unrolled, sub via wave-uniform branch — rule #20, proven clean in r8/r10).
// Partial goes straight to LDS red (no sArr registers).
#define COMPUTE(BUF, MT)                                                           \
  {                                                                                \
    const char* tb = (const char*)&tile[BUF][0];                                   \
    bf16x8 Bf[8];                                                                  \
    _Pragma("unroll")                                                              \
    for (int ks = 0; ks < 8; ++ks)                                                 \
      Bf[ks] = *reinterpret_cast<const bf16x8*>(tb + laneB[ks]);                   \
    float sq[4] = {0.f, 0.f, 0.f, 0.f};                                            \
    __builtin_amdgcn_s_setprio(1);                                                 \
    _Pragma("unroll")                                                              \
    for (int ctl = 0; ctl < 2; ++ctl) {                                            \
      f32x16 a;                                                                    \
      _Pragma("unroll")                                                            \
      for (int r = 0; r < 16; ++r) a[r] = 0.f;                                     \
      _Pragma("unroll")                                                            \
      for (int ks = 0; ks < 8; ++ks)                                               \
        a = __builtin_amdgcn_mfma_f32_32x32x16_bf16(A[ctl][ks], Bf[ks], a, 0,0,0); \
      a = __builtin_amdgcn_mfma_f32_32x32x16_bf16(A[ctl][8], B8c, a, 0, 0, 0);     \
      if (sub == 0) {                                                              \
        _Pragma("unroll")                                                          \
        for (int q = 0; q < 4; ++q)                                                \
          _Pragma("unroll")                                                        \
          for (int j = 0; j < 4; ++j)                                              \
            sq[q] += a[q * 4 + j] * (float)Bf[2 * ctl + (q >> 1)][4 * (q & 1) + j];\
      } else {                                                                     \
        _Pragma("unroll")                                                          \
        for (int q = 0; q < 4; ++q)                                                \
          _Pragma("unroll")                                                        \
          for (int j = 0; j < 4; ++j)                                              \
            sq[q] += a[q*4 + j] * (float)Bf[4 + 2*ctl + (q >> 1)][4*(q & 1) + j];  \
      }                                                                            \
    }                                                                              \
    __builtin_amdgcn_s_setprio(0);                                                 \
    float s = (sq[0] + sq[1]) + (sq[2] + sq[3]);                                   \
    s += __shfl_xor(s, 32);                                                        \
    if (hi == 0) red[o2][sub][MT][b32] = s;                                        \
  }

#define WAITV(N) asm volatile("s_waitcnt vmcnt(" #N ")" ::: "memory")
#define DRAIN()  asm volatile("s_waitcnt vmcnt(0) lgkmcnt(0)" ::: "memory")

// Counted-vmcnt iteration: wait own stage-T loads (leave stage T+1's 2 loads
// in flight), raw barrier, issue stage T+2 into the buffer everyone finished
// reading at T-1 (they passed this barrier), compute tile T.
#define ITER(T, VN)                                                                \
  {                                                                                \
    if (PREP) { WAITV(VN); } else { DRAIN(); }                                     \
    __builtin_amdgcn_s_barrier();                                                  \
    asm volatile("" ::: "memory");                                                 \
    if ((T) + 2 < NT) STAGE(((T) + 2) % 3, (T) + 2);                               \
    COMPUTE((T) % 3, (T));                                                         \
  }

// Block = 4 waves = 2 o's x 2 i-halves over one shared 256-row run. Each wave:
// A[2][9] stationary (72 regs, live ~146 total -> fits 3 waves/EU budget of
// 170). 3 LDS buffers, 2 stages in flight, vmcnt(2) steady (never 0 mid-loop).
template<int PREP>
__global__ __launch_bounds__(256, 3) void quad11(
    const float* __restrict__ x, const float* __restrict__ W,
    const __bf16* __restrict__ xq, const __bf16* __restrict__ Wq,
    const float* __restrict__ bias, float* __restrict__ out)
{
    __shared__ __align__(16) __bf16 tile[3][32 * 128];   // 3 x 8KB, swizzled
    __shared__ float red[2][2][NT][32];                  // [o2][sub][mt][b] 8KB

    const int tid  = threadIdx.x;
    const int lane = tid & 63;
    const int wave = tid >> 6;              // 0..3
    const int o2   = wave >> 1;             // which o of the block's 2
    const int sub  = wave & 1;              // i-half (0: i<64, 1: i>=64)
    const int b32  = lane & 31, hi = lane >> 5;

    // grid 1024 = 8 XCD x (16 o-pairs x 8 runs): same-XCD neighbors share a run
    const int bid = blockIdx.x;
    const int xcd = bid & 7, idx = bid >> 3;
    const int opair = idx & 15;
    const int run = xcd * 8 + (idx >> 4);   // 0..63
    const int o   = opair * 2 + o2;
    const long rbase = (long)run * (NT * 32);
    const float bias_o = bias[o];

    // ---- stationary A fragments: slot rows (sub*2+ctl)*32 + b32, k = hi*8+r ----
    bf16x8 A[2][9];
    #pragma unroll
    for (int ctl = 0; ctl < 2; ++ctl) {
        const int g = sub * 2 + ctl;
        if (PREP) {
            const __bf16* base = Wq + ((size_t)o * 128 + g * 32 + b32) * KE + hi * 8;
            #pragma unroll
            for (int ks = 0; ks < 9; ++ks)
                A[ctl][ks] = *reinterpret_cast<const bf16x8*>(base + ks * 16);
        } else {
            const int i = g * 32 + permSlot(b32);
            const float* wr = W + (size_t)o * WROW + (size_t)i * K129;
            #pragma unroll
            for (int ks = 0; ks < 8; ++ks) {
                bf16x8 f;
                #pragma unroll
                for (int r = 0; r < 8; ++r) f[r] = (__bf16)wr[ks * 16 + hi * 8 + r];
                A[ctl][ks] = f;
            }
            bf16x8 f;
            #pragma unroll
            for (int r = 0; r < 8; ++r) f[r] = (__bf16)0.f;
            if (hi == 0) f[0] = (__bf16)wr[128];         // wlin at k=128
            A[ctl][8] = f;
        }
    }

    // constant ks=8 B fragment: x~[b,128]=1, rest 0
    bf16x8 B8c;
    #pragma unroll
    for (int r = 0; r < 8; ++r) B8c[r] = (__bf16)0.f;
    if (hi == 0) B8c[0] = (__bf16)1.0f;

    // staging mapping: thread -> phys chunks {wave*128+lane, +64}; src inverse-XOR
    const int p0 = wave * 128 + lane;
    const int r0s = p0 >> 4, c0s = (p0 & 15) ^ (r0s & 15);
    const int p1 = p0 + 64;
    const int r1s = p1 >> 4, c1s = (p1 & 15) ^ (r1s & 15);

    // swizzled ds_read byte offsets (row = b32, logical chunk 2ks+hi)
    const int rm = b32 & 15;
    int laneB[8];
    #pragma unroll
    for (int ks = 0; ks < 8; ++ks)
        laneB[ks] = b32 * 256 + (((ks * 2 + hi) ^ rm) << 4);

    // prologue: 2 stages in flight (2 vmem ops each per thread)
    STAGE(0, 0);
    STAGE(1, 1);

    ITER(0, 2); ITER(1, 2); ITER(2, 2); ITER(3, 2);
    ITER(4, 2); ITER(5, 2); ITER(6, 2); ITER(7, 0);

    // ---- one-time cross-sub combine + store ----
    __syncthreads();
    if (sub == 0) {
        #pragma unroll
        for (int m = 0; m < NT / 2; ++m) {
            int mt = m * 2 + hi;
            out[(rbase + (long)mt * 32 + b32) * N_OUT + o] =
                red[o2][0][mt][b32] + red[o2][1][mt][b32] + bias_o;
        }
    }
}

extern "C" void kernel_launch(void* const* d_in, const int* in_sizes, int n_in,
                              void* d_out, int out_size, void* d_ws, size_t ws_size,
                              hipStream_t stream) {
    const float* x    = (const float*)d_in[0];
    const float* W    = (const float*)d_in[1];
    const float* bias = (const float*)d_in[2];
    float* out = (float*)d_out;

    const size_t need = (size_t)(XQ_ELEMS + WQ_ELEMS) * sizeof(__bf16);  // ~5.4 MB
    if (ws_size >= need) {
        __bf16* xq = (__bf16*)d_ws;
        __bf16* Wq = xq + XQ_ELEMS;
        prep<<<1312, 256, 0, stream>>>(x, W, xq, Wq);
        quad11<1><<<1024, 256, 0, stream>>>(x, W, xq, Wq, bias, out);
    } else {
        quad11<0><<<1024, 256, 0, stream>>>(x, W, (const __bf16*)nullptr,
                                            (const __bf16*)nullptr, bias, out);
    }
}